// Round 12
// baseline (1273.967 us; speedup 1.0000x reference)
//
#include <hip/hip_runtime.h>
#include <hip/hip_fp16.h>
#include <hip/hip_cooperative_groups.h>

namespace cg = cooperative_groups;

// B=64, N=64, D=128, L=4, T=10. Single cooperative mega-kernel: prep ->
// embed_ab -> 4x(edge -> node) with grid.sync() between phases. All phase
// bodies are r10-verbatim (numerics identical, absmax 7.8e-3 expected).

typedef _Float16 f16;
typedef _Float16 f16x4 __attribute__((ext_vector_type(4)));
typedef _Float16 f16x8 __attribute__((ext_vector_type(8)));
typedef float f32x4 __attribute__((ext_vector_type(4)));

union H2x4 { f16x8 v; __half2 h[4]; };

__device__ __forceinline__ float bf2f(unsigned short u) {
    union { unsigned int i; float f; } v; v.i = ((unsigned int)u) << 16; return v.f;
}
__device__ __forceinline__ unsigned short f2bf(float f) {
    union { float f; unsigned int i; } v; v.f = f;
    unsigned int x = v.i;
    return (unsigned short)((x + 0x7fffu + ((x >> 16) & 1u)) >> 16);
}
__device__ __forceinline__ float silu_f(float x) {
    float e = __builtin_amdgcn_exp2f(-1.44269504088896f * x);
    return x * __builtin_amdgcn_rcpf(1.0f + e);
}
__device__ __forceinline__ __half2 silu_h2(__half2 x, __half2 kf, __half2 one2) {
    __half2 e = h2exp2(__hmul2(x, kf));
    return __hmul2(x, h2rcp(__hadd2(one2, e)));
}

struct Ptrs { const void* p[14]; };
// p: 0 pos, 1 embed, 2 ew1, 3 eb1, 4 ew2, 5 eb2, 6 nw1, 7 nb1, 8 nw2,
//    9 nb2, 10 lng, 11 lnb, 12 ow, 13 ob

__device__ __forceinline__ float ldf(const void* p, int i, int bf) {
    return bf ? bf2f(((const unsigned short*)p)[i]) : ((const float*)p)[i];
}

// sc (fp32) offsets: pos 0(12288) embed 12288(1280) wd 13568(512)
// eb1 14080 eb2 14592 nb1 15104 nb2 15616 lng 16128 lnb 16640 (512 each)
// ow 17152(384) ob 17536(3). total 17539.
#define FRAG_TOTAL 49152
#define SMALL_TOTAL 17539

__global__ void mega_kernel(
    Ptrs ptrs, const int* an, f16* Wswz, float* sc,
    f16* h16, f16* a16, f16* b16, f16* m16, void* out)
{
    __shared__ f16 Wlds[8192];         // 16 KB: edge phase-A weights
    __shared__ f16 Ssh[64 * 136];      // 17.4 KB: edge S / node relay+psh
    __shared__ float msum[256];        // 1 KB: edge epilogue / node s1+s2
    __shared__ __half2 wd2_sh[64];
    __shared__ int flgsh;

    cg::grid_group grid = cg::this_grid();
    int blk = blockIdx.x, t = threadIdx.x;
    int lane = t & 63, w = t >> 6;
    int wr = w & 1, wc = w >> 1;
    int m_ = lane & 15, q_ = lane >> 4;
    const float* posC = sc;

    // ---------------- phase 0: prep (dtype-detect + swizzle + small) -----
    if (t < 64) {
        int ex = (((const unsigned short*)ptrs.p[0])[t * 2] >> 7) & 0xFF;
        unsigned long long mk = __ballot(ex >= 110 && ex <= 135);
        if (t == 0) flgsh = (__popcll(mk) >= 40) ? 1 : 0;
    }
    __syncthreads();
    {
        int bf = flgsh;
        for (int gid = blk * 256 + t; gid < FRAG_TOTAL + SMALL_TOTAL;
             gid += gridDim.x * 256) {
            if (gid < FRAG_TOTAL) {
                int lay = gid / 12288;
                int r   = gid % 12288;
                const void* src; int base, rowoff = 0, r2;
                if (r < 6144) {
                    int mat = r >> 11; r2 = r & 2047;
                    if (mat == 0)      { src = ptrs.p[2]; base = lay * 32896; }
                    else if (mat == 1) { src = ptrs.p[2]; base = lay * 32896; rowoff = 128; }
                    else               { src = ptrs.p[4]; base = lay * 16384; }
                } else if (r < 10240) {
                    r2 = r - 6144; src = ptrs.p[6]; base = lay * 32768;
                } else {
                    r2 = r - 10240; src = ptrs.p[8]; base = lay * 16384;
                }
                int s = r2 >> 9, c = (r2 >> 6) & 7, l = r2 & 63;
                int row0 = rowoff + s * 32 + ((l >> 4) << 3);
                int col  = (c << 4) + (l & 15);
                f16x8 v;
#pragma unroll
                for (int jj = 0; jj < 8; jj++)
                    v[jj] = (f16)ldf(src, base + (row0 + jj) * 128 + col, bf);
                *(f16x8*)(Wswz + gid * 8) = v;
            } else {
                int sid = gid - FRAG_TOTAL;
                const void* src; int i;
                if      (sid < 12288) { src = ptrs.p[0]; i = sid; }
                else if (sid < 13568) { src = ptrs.p[1]; i = sid - 12288; }
                else if (sid < 14080) { int k = sid - 13568;
                                        src = ptrs.p[2]; i = (k >> 7) * 32896 + 32768 + (k & 127); }
                else if (sid < 14592) { src = ptrs.p[3];  i = sid - 14080; }
                else if (sid < 15104) { src = ptrs.p[5];  i = sid - 14592; }
                else if (sid < 15616) { src = ptrs.p[7];  i = sid - 15104; }
                else if (sid < 16128) { src = ptrs.p[9];  i = sid - 15616; }
                else if (sid < 16640) { src = ptrs.p[10]; i = sid - 16128; }
                else if (sid < 17152) { src = ptrs.p[11]; i = sid - 16640; }
                else if (sid < 17536) { src = ptrs.p[12]; i = sid - 17152; }
                else                  { src = ptrs.p[13]; i = sid - 17536; }
                sc[sid] = ldf(src, i, bf);
            }
        }
    }
    __threadfence();
    grid.sync();

    // ---------------- phase 1: embed + layer-0 a,b -----------------------
    for (int g = blk; g < 256; g += gridDim.x) {
        int row0 = g << 4;
        const float* emb = sc + 12288;
        const float* eb1C = sc + 14080;
        int a = an[row0 + m_];
        a = a < 0 ? 0 : (a > 9 ? 9 : a);
        f16x8 afrag[4];
#pragma unroll
        for (int s = 0; s < 4; s++) {
            f32x4 u0 = *(const f32x4*)(emb + a * 128 + s * 32 + q_ * 8);
            f32x4 u1 = *(const f32x4*)(emb + a * 128 + s * 32 + q_ * 8 + 4);
            f16x8 hv;
#pragma unroll
            for (int e = 0; e < 4; e++) { hv[e] = (f16)u0[e]; hv[e + 4] = (f16)u1[e]; }
            afrag[s] = hv;
            if (w == 0)
                *(f16x8*)(h16 + (row0 + m_) * 128 + s * 32 + q_ * 8) = hv;
        }
#pragma unroll
        for (int mat = 0; mat < 2; mat++) {
            const f16* W = mat ? (Wswz + 16384) : Wswz;
            f16* o       = mat ? b16 : a16;
#pragma unroll
            for (int cc = 0; cc < 2; cc++) {
                int c = 2 * w + cc;
                float init = mat ? 0.0f : eb1C[c * 16 + m_];
                f32x4 acc = { init, init, init, init };
#pragma unroll
                for (int s = 0; s < 4; s++) {
                    f16x8 bfr = *(const f16x8*)(W + ((s * 8 + c) * 64 + lane) * 8);
                    acc = __builtin_amdgcn_mfma_f32_16x16x32_f16(afrag[s], bfr, acc, 0, 0, 0);
                }
#pragma unroll
                for (int r = 0; r < 4; r++)
                    o[(row0 + q_ * 4 + r) * 128 + c * 16 + m_] = (f16)acc[r];
            }
        }
    }
    __threadfence();
    grid.sync();

    // ---------------- layers ---------------------------------------------
    for (int lay = 0; lay < 4; lay++) {
        const f16* wl = Wswz + lay * 98304;
        const f16* ew2 = wl + 32768;
        const float* wdC  = sc + 13568 + lay * 128;
        const float* eb2C = sc + 14592 + lay * 128;
        const float* nb1C = sc + 15104 + lay * 128;
        const float* nb2C = sc + 15616 + lay * 128;
        const float* lngC = sc + 16128 + lay * 128;
        const float* lnbC = sc + 16640 + lay * 128;

        // ---- edge: m_i = mean_j silu(silu(pre_ij) @ ew2 + eb2) ----
        // r10 body; per-layer hoists: Wlds (phase A), bfB regs (phase B),
        // wd2/wd_r, ebias. Each block loops rows 4*eb..4*eb+3.
#pragma unroll
        for (int k = 0; k < 4; k++) {
            int idx = (k * 256 + t) * 8;
            *(f16x8*)(Wlds + idx) = *(const f16x8*)(ew2 + idx);
        }
        f16x8 bfB[2][4];
#pragma unroll
        for (int s2 = 0; s2 < 2; s2++)
#pragma unroll
            for (int c = 0; c < 4; c++)
                bfB[s2][c] = *(const f16x8*)(ew2 +
                    (((s2 + 2) * 8 + wc * 4 + c) * 64 + lane) * 8);
        if (t >= 64 && t < 128) {
            int u = t - 64;
            wd2_sh[u] = __floats2half2_rn(wdC[2 * u], wdC[2 * u + 1]);
        }
        float ebias[4];
#pragma unroll
        for (int c = 0; c < 4; c++) ebias[c] = eb2C[(wc * 4 + c) * 16 + m_];
        int j  = t >> 2;
        int cb = (t & 3) * 32;
        __half2 kf   = __floats2half2_rn(-1.44269504f, -1.44269504f);
        __half2 one2 = __floats2half2_rn(1.0f, 1.0f);
        __syncthreads();
        H2x4 wd_r[4];
#pragma unroll
        for (int k = 0; k < 4; k++)
            wd_r[k].v = *(const f16x8*)((const f16*)wd2_sh + cb + k * 8);

        for (int eb = blk; eb < 1024; eb += gridDim.x) {
            int ig0 = eb * 4;
            int b = ig0 >> 6;
            int jg = b * 64 + j;
            float pxj = posC[jg * 3 + 0], pyj = posC[jg * 3 + 1], pzj = posC[jg * 3 + 2];
            for (int ii = 0; ii < 4; ii++) {
                int ig = ig0 + ii;
                float xi = posC[ig * 3 + 0], yi = posC[ig * 3 + 1], zi = posC[ig * 3 + 2];
                float dx = xi - pxj, dy = yi - pyj, dz = zi - pzj;
                __half dh = __float2half_rn(dx * dx + dy * dy + dz * dz);
                __half2 ds2 = __halves2half2(dh, dh);
#pragma unroll
                for (int k = 0; k < 4; k++) {
                    H2x4 av, bv, sv;
                    av.v = *(const f16x8*)(a16 + ig * 128 + cb + k * 8);
                    bv.v = *(const f16x8*)(b16 + jg * 128 + cb + k * 8);
#pragma unroll
                    for (int e = 0; e < 4; e++) {
                        __half2 pre = __hfma2(ds2, wd_r[k].h[e],
                                              __hadd2(av.h[e], bv.h[e]));
                        sv.h[e] = silu_h2(pre, kf, one2);
                    }
                    *(f16x8*)(Ssh + j * 136 + cb + k * 8) = sv.v;
                }
                __syncthreads();       // S ready; prev msum reads done

                f32x4 acc[4][2];
#pragma unroll
                for (int c = 0; c < 4; c++) {
                    acc[c][0] = (f32x4){ ebias[c], ebias[c], ebias[c], ebias[c] };
                    acc[c][1] = acc[c][0];
                }
#pragma unroll
                for (int s = 0; s < 2; s++) {
                    f16x8 bfr[4];
#pragma unroll
                    for (int c = 0; c < 4; c++)
                        bfr[c] = *(const f16x8*)(Wlds + ((s * 8 + wc * 4 + c) * 64 + lane) * 8);
#pragma unroll
                    for (int mb = 0; mb < 2; mb++) {
                        f16x8 af = *(const f16x8*)(Ssh + ((wr * 2 + mb) * 16 + m_) * 136 + s * 32 + q_ * 8);
#pragma unroll
                        for (int c = 0; c < 4; c++)
                            acc[c][mb] = __builtin_amdgcn_mfma_f32_16x16x32_f16(af, bfr[c], acc[c][mb], 0, 0, 0);
                    }
                }
#pragma unroll
                for (int s2 = 0; s2 < 2; s2++) {
#pragma unroll
                    for (int mb = 0; mb < 2; mb++) {
                        f16x8 af = *(const f16x8*)(Ssh + ((wr * 2 + mb) * 16 + m_) * 136 + (s2 + 2) * 32 + q_ * 8);
#pragma unroll
                        for (int c = 0; c < 4; c++)
                            acc[c][mb] = __builtin_amdgcn_mfma_f32_16x16x32_f16(af, bfB[s2][c], acc[c][mb], 0, 0, 0);
                    }
                }
#pragma unroll
                for (int c = 0; c < 4; c++) {
                    float scv = 0.0f;
#pragma unroll
                    for (int mb = 0; mb < 2; mb++)
#pragma unroll
                        for (int r = 0; r < 4; r++)
                            scv += silu_f(acc[c][mb][r]);
                    scv += __shfl_xor(scv, 16);
                    scv += __shfl_xor(scv, 32);
                    if (lane < 16)
                        msum[wr * 128 + (wc * 4 + c) * 16 + lane] = scv;
                }
                __syncthreads();       // msum ready; all S reads done
                if (t < 128) {
                    float mv = (msum[t] + msum[128 + t]) * (1.0f / 64.0f);
                    m16[ig * 128 + t] = (f16)mv;
                }
            }
        }
        __threadfence();
        grid.sync();

        // ---- node: u=silu([h|m]@nw1+nb1); x=h+u@nw2+nb2; h'=LN(x)*g+b ----
        const f16* nw1s = wl + 49152;
        const f16* nw2s = wl + 81920;
        f16* relay = Ssh;                       // 16*136 f16 = 4.3 KB
        float* s1sh = msum;                     // [4][16]
        float* s2sh = msum + 64;                // [4][16]
        float* pshf = (float*)(Ssh + 4608);     // [4][16][3] (final only)

        for (int g = blk; g < 256; g += gridDim.x) {
            __syncthreads();           // relay reuse guard across g
            int row0 = g << 4;
            f16x8 af[8];
#pragma unroll
            for (int s = 0; s < 4; s++) {
                af[s]     = *(const f16x8*)(h16 + (row0 + m_) * 128 + s * 32 + q_ * 8);
                af[s + 4] = *(const f16x8*)(m16 + (row0 + m_) * 128 + s * 32 + q_ * 8);
            }
#pragma unroll
            for (int cc = 0; cc < 2; cc++) {
                int c = 2 * w + cc;
                float e = nb1C[c * 16 + m_];
                f32x4 acc = { e, e, e, e };
#pragma unroll
                for (int s = 0; s < 8; s++) {
                    f16x8 bfr = *(const f16x8*)(nw1s + ((s * 8 + c) * 64 + lane) * 8);
                    acc = __builtin_amdgcn_mfma_f32_16x16x32_f16(af[s], bfr, acc, 0, 0, 0);
                }
#pragma unroll
                for (int r = 0; r < 4; r++)
                    relay[(q_ * 4 + r) * 136 + c * 16 + m_] = (f16)silu_f(acc[r]);
            }
            __syncthreads();
            f16x8 uf[4];
#pragma unroll
            for (int s = 0; s < 4; s++)
                uf[s] = *(const f16x8*)(relay + m_ * 136 + s * 32 + q_ * 8);
            float x[2][4];
#pragma unroll
            for (int cc = 0; cc < 2; cc++) {
                int c = 2 * w + cc;
                float e = nb2C[c * 16 + m_];
                f32x4 acc = { e, e, e, e };
#pragma unroll
                for (int s = 0; s < 4; s++) {
                    f16x8 bfr = *(const f16x8*)(nw2s + ((s * 8 + c) * 64 + lane) * 8);
                    acc = __builtin_amdgcn_mfma_f32_16x16x32_f16(uf[s], bfr, acc, 0, 0, 0);
                }
#pragma unroll
                for (int r = 0; r < 4; r++)
                    x[cc][r] = acc[r] + (float)h16[(row0 + q_ * 4 + r) * 128 + c * 16 + m_];
            }
            float s1p[4], s2p[4];
#pragma unroll
            for (int r = 0; r < 4; r++) {
                s1p[r] = x[0][r] + x[1][r];
                s2p[r] = x[0][r] * x[0][r] + x[1][r] * x[1][r];
            }
#pragma unroll
            for (int msk = 1; msk < 16; msk <<= 1)
#pragma unroll
                for (int r = 0; r < 4; r++) {
                    s1p[r] += __shfl_xor(s1p[r], msk);
                    s2p[r] += __shfl_xor(s2p[r], msk);
                }
            if (m_ == 0)
#pragma unroll
                for (int r = 0; r < 4; r++) {
                    s1sh[w * 16 + q_ * 4 + r] = s1p[r];
                    s2sh[w * 16 + q_ * 4 + r] = s2p[r];
                }
            __syncthreads();

            if (lay < 3) {
                const f16* waN = Wswz + (lay + 1) * 98304;
                const f16* wbN = waN + 16384;
                const float* eb1N = sc + 14080 + (lay + 1) * 128;
                float mu[4], rs[4];
#pragma unroll
                for (int r = 0; r < 4; r++) {
                    int row = q_ * 4 + r;
                    float S1 = s1sh[row] + s1sh[16 + row] + s1sh[32 + row] + s1sh[48 + row];
                    float S2 = s2sh[row] + s2sh[16 + row] + s2sh[32 + row] + s2sh[48 + row];
                    mu[r] = S1 * (1.0f / 128.0f);
                    float var = S2 * (1.0f / 128.0f) - mu[r] * mu[r];
                    rs[r] = rsqrtf(var + 1e-5f);
                }
#pragma unroll
                for (int cc = 0; cc < 2; cc++) {
                    int c = 2 * w + cc;
#pragma unroll
                    for (int r = 0; r < 4; r++) {
                        int col = c * 16 + m_;
                        int row = row0 + q_ * 4 + r;
                        float y = (x[cc][r] - mu[r]) * rs[r] * lngC[col] + lnbC[col];
                        h16[row * 128 + col] = (f16)y;
                        relay[(q_ * 4 + r) * 136 + col] = (f16)y;
                    }
                }
                __syncthreads();
                f16x8 hf[4];
#pragma unroll
                for (int s = 0; s < 4; s++)
                    hf[s] = *(const f16x8*)(relay + m_ * 136 + s * 32 + q_ * 8);
#pragma unroll
                for (int mat = 0; mat < 2; mat++) {
                    const f16* W = mat ? wbN : waN;
                    f16* o       = mat ? b16 : a16;
#pragma unroll
                    for (int cc = 0; cc < 2; cc++) {
                        int c = 2 * w + cc;
                        float init = mat ? 0.0f : eb1N[c * 16 + m_];
                        f32x4 acc = { init, init, init, init };
#pragma unroll
                        for (int s = 0; s < 4; s++) {
                            f16x8 bfr = *(const f16x8*)(W + ((s * 8 + c) * 64 + lane) * 8);
                            acc = __builtin_amdgcn_mfma_f32_16x16x32_f16(hf[s], bfr, acc, 0, 0, 0);
                        }
#pragma unroll
                        for (int r = 0; r < 4; r++)
                            o[(row0 + q_ * 4 + r) * 128 + c * 16 + m_] = (f16)acc[r];
                    }
                }
            } else {
                const float* owC = sc + 17152;
                const float* obC = sc + 17536;
                float p[3][4];
#pragma unroll
                for (int r = 0; r < 4; r++) {
                    int row = q_ * 4 + r;
                    float S1 = s1sh[row] + s1sh[16 + row] + s1sh[32 + row] + s1sh[48 + row];
                    float S2 = s2sh[row] + s2sh[16 + row] + s2sh[32 + row] + s2sh[48 + row];
                    float mu = S1 * (1.0f / 128.0f);
                    float var = S2 * (1.0f / 128.0f) - mu * mu;
                    float rs = rsqrtf(var + 1e-5f);
                    float p0 = 0.0f, p1 = 0.0f, p2 = 0.0f;
#pragma unroll
                    for (int cc = 0; cc < 2; cc++) {
                        int col = (2 * w + cc) * 16 + m_;
                        float y = (x[cc][r] - mu) * rs * lngC[col] + lnbC[col];
                        p0 += y * owC[col * 3 + 0];
                        p1 += y * owC[col * 3 + 1];
                        p2 += y * owC[col * 3 + 2];
                    }
                    p[0][r] = p0; p[1][r] = p1; p[2][r] = p2;
                }
#pragma unroll
                for (int msk = 1; msk < 16; msk <<= 1)
#pragma unroll
                    for (int k = 0; k < 3; k++)
#pragma unroll
                        for (int r = 0; r < 4; r++)
                            p[k][r] += __shfl_xor(p[k][r], msk);
                if (m_ == 0)
#pragma unroll
                    for (int r = 0; r < 4; r++)
#pragma unroll
                        for (int k = 0; k < 3; k++)
                            pshf[(w * 16 + q_ * 4 + r) * 3 + k] = p[k][r];
                __syncthreads();
                if (t < 16) {
                    int row = row0 + t;
                    int bf = flgsh;    // set in phase 0, stable since
#pragma unroll
                    for (int k = 0; k < 3; k++) {
                        float v = pshf[(t) * 3 + k] + pshf[(16 + t) * 3 + k] +
                                  pshf[(32 + t) * 3 + k] + pshf[(48 + t) * 3 + k] +
                                  obC[k];
                        if (bf) ((unsigned short*)out)[row * 3 + k] = f2bf(v);
                        else    ((float*)out)[row * 3 + k] = v;
                    }
                }
            }
        }
        __threadfence();
        grid.sync();
    }
}

extern "C" void kernel_launch(void* const* d_in, const int* in_sizes, int n_in,
                              void* d_out, int out_size, void* d_ws, size_t ws_size,
                              hipStream_t stream)
{
    const int* an = (const int*)d_in[1];

    char* ws = (char*)d_ws;
    float* sc   = (float*)(ws + 1024);              // 70 KB
    f16*   Wswz = (f16*)(ws + (128u << 10));        // 768 KB
    f16*   h16  = (f16*)(ws + (1u << 20));          // 1 MB
    f16*   a16  = (f16*)(ws + (2u << 20));
    f16*   b16  = (f16*)(ws + (3u << 20));
    f16*   m16  = (f16*)(ws + (4u << 20));          // total 5 MB

    Ptrs ptrs;
    const int src_idx[14] = {0, 2, 3, 4, 5, 6, 7, 8, 9, 10, 11, 12, 13, 14};
    for (int k = 0; k < 14; k++) ptrs.p[k] = d_in[src_idx[k]];

    int maxb = 0;
    hipOccupancyMaxActiveBlocksPerMultiprocessor(&maxb, mega_kernel, 256, 0);
    if (maxb < 1) maxb = 1;
    unsigned int grid = (unsigned int)maxb * 256u;
    if (grid > 1024u) grid = 1024u;

    void* outp = d_out;
    void* args[] = { &ptrs, &an, &Wswz, &sc, &h16, &a16, &b16, &m16, &outp };
    hipLaunchCooperativeKernel((void*)mega_kernel, dim3(grid), dim3(256),
                               args, 0, stream);
}

// Round 13
// 215.299 us; speedup vs baseline: 5.9172x; 5.9172x over previous
//
#include <hip/hip_runtime.h>
#include <hip/hip_fp16.h>

// B=64, N=64, D=128, L=4, T=10. Float tensors may arrive as bf16 OR fp32 —
// detected per-block (wave-0 ballot on positions' u16 exponent pattern).
// r10 restored verbatim: proven optimum (215.5 us). r8/r9/r11/r12 structural
// alternatives all regressed (occupancy loss / barrier overhead / VGPR
// spills / grid.sync cost ~300us per barrier on 8 XCDs).

typedef _Float16 f16;
typedef _Float16 f16x4 __attribute__((ext_vector_type(4)));
typedef _Float16 f16x8 __attribute__((ext_vector_type(8)));
typedef float f32x4 __attribute__((ext_vector_type(4)));

union H2x4 { f16x8 v; __half2 h[4]; };

__device__ __forceinline__ float bf2f(unsigned short u) {
    union { unsigned int i; float f; } v; v.i = ((unsigned int)u) << 16; return v.f;
}
__device__ __forceinline__ unsigned short f2bf(float f) {
    union { float f; unsigned int i; } v; v.f = f;
    unsigned int x = v.i;
    return (unsigned short)((x + 0x7fffu + ((x >> 16) & 1u)) >> 16);
}
// fast silu (f32): mul, v_exp_f32, add, v_rcp_f32, mul
__device__ __forceinline__ float silu_f(float x) {
    float e = __builtin_amdgcn_exp2f(-1.44269504088896f * x);
    return x * __builtin_amdgcn_rcpf(1.0f + e);
}
// packed f16 silu on a half2 pair
__device__ __forceinline__ __half2 silu_h2(__half2 x, __half2 kf, __half2 one2) {
    __half2 e = h2exp2(__hmul2(x, kf));
    return __hmul2(x, h2rcp(__hadd2(one2, e)));
}

struct Ptrs { const void* p[14]; };
// p: 0 pos, 1 embed, 2 ew1, 3 eb1, 4 ew2, 5 eb2, 6 nw1, 7 nb1, 8 nw2,
//    9 nb2, 10 lng, 11 lnb, 12 ow, 13 ob

__device__ __forceinline__ float ldf(const void* p, int i, int bf) {
    return bf ? bf2f(((const unsigned short*)p)[i]) : ((const float*)p)[i];
}

// small canon (fp32) offsets: pos 0(12288) embed 12288(1280) wd 13568(512)
// eb1 14080 eb2 14592 nb1 15104 nb2 15616 lng 16128 lnb 16640 (512 each)
// ow 17152(384) ob 17536(3). total 17539.
#define FRAG_TOTAL 49152           // 393216 swizzled f16 elems / 8 per fragment
#define SMALL_TOTAL 17539

// Swizzle weights into f16 B-fragment order for mfma_f32_16x16x32_f16.
// One thread builds one 8-elem fragment (vectorized, r8-proven): frag f ->
//   dst[f*8+j] = W[rowoff + s*32 + ((l>>4)<<3) + j][c*16 + (l&15)],
//   f = (s*8+c)*64+l. Per-layer frag bases: wa 0, wb 2048, ew2 4096,
//   nw1 6144, nw2 10240; layer stride 12288 frags.
__global__ __launch_bounds__(256) void prep_kernel(
    Ptrs ptrs, f16* dst, float* sc)
{
    __shared__ int flgsh;
    int t = threadIdx.x;
    if (t < 64) {
        int ex = (((const unsigned short*)ptrs.p[0])[t * 2] >> 7) & 0xFF;
        unsigned long long m = __ballot(ex >= 110 && ex <= 135);
        if (t == 0) flgsh = (__popcll(m) >= 40) ? 1 : 0;
    }
    __syncthreads();
    int bf = flgsh;

    int gid = blockIdx.x * 256 + t;
    if (gid < FRAG_TOTAL) {
        int lay = gid / 12288;
        int r   = gid % 12288;
        const void* src; int base, rowoff = 0, r2;
        if (r < 6144) {
            int mat = r >> 11; r2 = r & 2047;
            if (mat == 0)      { src = ptrs.p[2]; base = lay * 32896; }
            else if (mat == 1) { src = ptrs.p[2]; base = lay * 32896; rowoff = 128; }
            else               { src = ptrs.p[4]; base = lay * 16384; }
        } else if (r < 10240) {
            r2 = r - 6144; src = ptrs.p[6]; base = lay * 32768;
        } else {
            r2 = r - 10240; src = ptrs.p[8]; base = lay * 16384;
        }
        int s = r2 >> 9, c = (r2 >> 6) & 7, l = r2 & 63;
        int row0 = rowoff + s * 32 + ((l >> 4) << 3);
        int col  = (c << 4) + (l & 15);
        f16x8 v;
#pragma unroll
        for (int jj = 0; jj < 8; jj++)
            v[jj] = (f16)ldf(src, base + (row0 + jj) * 128 + col, bf);
        *(f16x8*)(dst + gid * 8) = v;
    } else {
        int sid = gid - FRAG_TOTAL;
        if (sid >= SMALL_TOTAL) return;
        const void* src; int i;
        if      (sid < 12288) { src = ptrs.p[0]; i = sid; }
        else if (sid < 13568) { src = ptrs.p[1]; i = sid - 12288; }
        else if (sid < 14080) { int k = sid - 13568;
                                src = ptrs.p[2]; i = (k >> 7) * 32896 + 32768 + (k & 127); }
        else if (sid < 14592) { src = ptrs.p[3];  i = sid - 14080; }
        else if (sid < 15104) { src = ptrs.p[5];  i = sid - 14592; }
        else if (sid < 15616) { src = ptrs.p[7];  i = sid - 15104; }
        else if (sid < 16128) { src = ptrs.p[9];  i = sid - 15616; }
        else if (sid < 16640) { src = ptrs.p[10]; i = sid - 16128; }
        else if (sid < 17152) { src = ptrs.p[11]; i = sid - 16640; }
        else if (sid < 17536) { src = ptrs.p[12]; i = sid - 17152; }
        else                  { src = ptrs.p[13]; i = sid - 17536; }
        sc[sid] = ldf(src, i, bf);
    }
}

// h = embed[an]; a = h@wa + eb1; b = h@wb.
// 256 threads / 16 rows: wave w computes output cols c = 2w, 2w+1 (both mats).
__global__ __launch_bounds__(256) void embed_ab_kernel(
    const int* an, const float* sc, const f16* wa, const f16* wb,
    const float* eb1C, f16* h16, f16* a16, f16* b16)
{
    int t = threadIdx.x;
    int w = t >> 6, lane = t & 63;
    int row0 = blockIdx.x << 4;
    int m_ = lane & 15, q_ = lane >> 4;
    const float* emb = sc + 12288;
    int a = an[row0 + m_];
    a = a < 0 ? 0 : (a > 9 ? 9 : a);
    f16x8 afrag[4];
#pragma unroll
    for (int s = 0; s < 4; s++) {
        f32x4 u0 = *(const f32x4*)(emb + a * 128 + s * 32 + q_ * 8);
        f32x4 u1 = *(const f32x4*)(emb + a * 128 + s * 32 + q_ * 8 + 4);
        f16x8 hv;
#pragma unroll
        for (int e = 0; e < 4; e++) { hv[e] = (f16)u0[e]; hv[e + 4] = (f16)u1[e]; }
        afrag[s] = hv;
        if (w == 0)
            *(f16x8*)(h16 + (row0 + m_) * 128 + s * 32 + q_ * 8) = hv;
    }
#pragma unroll
    for (int mat = 0; mat < 2; mat++) {
        const f16* W = mat ? wb : wa;
        f16* out     = mat ? b16 : a16;
#pragma unroll
        for (int cc = 0; cc < 2; cc++) {
            int c = 2 * w + cc;
            float init = mat ? 0.0f : eb1C[c * 16 + m_];
            f32x4 acc = { init, init, init, init };
#pragma unroll
            for (int s = 0; s < 4; s++) {
                f16x8 bfr = *(const f16x8*)(W + ((s * 8 + c) * 64 + lane) * 8);
                acc = __builtin_amdgcn_mfma_f32_16x16x32_f16(afrag[s], bfr, acc, 0, 0, 0);
            }
#pragma unroll
            for (int r = 0; r < 4; r++)
                out[(row0 + q_ * 4 + r) * 128 + c * 16 + m_] = (f16)acc[r];
        }
    }
}

// Block per (b,i): m_i = mean_j silu(silu(pre_ij) @ ew2 + eb2)
// r7-proven structure with the mid-GEMM barrier pair removed:
//   phase A (s=0,1) ew2 staged to 16 KB Wlds once; phase B (s=2,3) fragments
//   prefetched coalesced into registers before the S-build (latency hidden)
//   and MFMA'd directly from registers. 4 barriers, LDS ~34 KB, 4 blocks/CU.
__global__ __launch_bounds__(256) void edge_kernel(
    const float* sc, const f16* a16, const f16* b16,
    const f16* ew2_swz, const float* eb2C, const float* wdC, f16* m_out)
{
    __shared__ f16 Wlds[8192];         // phase A of swizzled ew2, 16 KB
    __shared__ f16 S[64 * 136];        // silu(pre), stride 136
    __shared__ __half2 wd2_sh[64];
    __shared__ float dsq_sh[64];

    int t  = threadIdx.x;
    int ig = blockIdx.x;               // b*64 + i
    int b  = ig >> 6;
    const float* posC = sc;
    int lane = t & 63, w = t >> 6;
    int wr = w & 1, wc = w >> 1;

    // stage phase A: fragments s=0,1 == ew2_swz[0..8191]
#pragma unroll
    for (int k = 0; k < 4; k++) {
        int idx = (k * 256 + t) * 8;
        *(f16x8*)(Wlds + idx) = *(const f16x8*)(ew2_swz + idx);
    }
    // prefetch phase B (s=2,3) B-fragments straight into registers —
    // coalesced 16 B/lane; latency hides behind wd/dsq staging + S-build
    f16x8 bfB[2][4];
#pragma unroll
    for (int s2 = 0; s2 < 2; s2++)
#pragma unroll
        for (int c = 0; c < 4; c++)
            bfB[s2][c] = *(const f16x8*)(ew2_swz +
                (((s2 + 2) * 8 + wc * 4 + c) * 64 + lane) * 8);

    if (t >= 64 && t < 128) {
        int u = t - 64;
        wd2_sh[u] = __floats2half2_rn(wdC[2 * u], wdC[2 * u + 1]);
    }
    if (t < 64) {
        float xi = posC[ig * 3 + 0], yi = posC[ig * 3 + 1], zi = posC[ig * 3 + 2];
        int jg = b * 64 + t;
        float dx = xi - posC[jg * 3 + 0];
        float dy = yi - posC[jg * 3 + 1];
        float dz = zi - posC[jg * 3 + 2];
        dsq_sh[t] = dx * dx + dy * dy + dz * dz;
    }
    __syncthreads();

    // S[j][d] = silu(a_i[d] + b_j[d] + dsq[j]*wd[d]) — packed f16.
    // thread -> row j = t>>2, cols [(t&3)*32, +32)
    {
        int j  = t >> 2;
        int cb = (t & 3) * 32;
        float dsf = dsq_sh[j];
        __half dh = __float2half_rn(dsf);
        __half2 ds2 = __halves2half2(dh, dh);
        __half2 kf   = __floats2half2_rn(-1.44269504f, -1.44269504f);
        __half2 one2 = __floats2half2_rn(1.0f, 1.0f);
        H2x4 a_r[4], wd_r[4];
#pragma unroll
        for (int k = 0; k < 4; k++) {
            a_r[k].v  = *(const f16x8*)(a16 + ig * 128 + cb + k * 8);
            wd_r[k].v = *(const f16x8*)((const f16*)wd2_sh + cb + k * 8);
        }
#pragma unroll
        for (int k = 0; k < 4; k++) {
            H2x4 bv, sv;
            bv.v = *(const f16x8*)(b16 + (b * 64 + j) * 128 + cb + k * 8);
#pragma unroll
            for (int e = 0; e < 4; e++) {
                __half2 pre = __hfma2(ds2, wd_r[k].h[e],
                                      __hadd2(a_r[k].h[e], bv.h[e]));
                sv.h[e] = silu_h2(pre, kf, one2);
            }
            *(f16x8*)(S + j * 136 + cb + k * 8) = sv.v;
        }
    }
    __syncthreads();                   // S + Wlds(A) ready

    // GEMM 64x128 @ 128x128, 2x2 split:
    // wave w: wr (rows wr*32..+32), wc (col tiles wc*4..wc*4+3)
    int m_ = lane & 15, q_ = lane >> 4;
    f32x4 acc[4][2];
#pragma unroll
    for (int c = 0; c < 4; c++) {
        float e = eb2C[(wc * 4 + c) * 16 + m_];
        acc[c][0] = (f32x4){ e, e, e, e };
        acc[c][1] = acc[c][0];
    }
    // phase A: s = 0,1 from LDS
#pragma unroll
    for (int s = 0; s < 2; s++) {
        f16x8 bfr[4];
#pragma unroll
        for (int c = 0; c < 4; c++)
            bfr[c] = *(const f16x8*)(Wlds + ((s * 8 + wc * 4 + c) * 64 + lane) * 8);
#pragma unroll
        for (int mb = 0; mb < 2; mb++) {
            f16x8 af = *(const f16x8*)(S + ((wr * 2 + mb) * 16 + m_) * 136 + s * 32 + q_ * 8);
#pragma unroll
            for (int c = 0; c < 4; c++)
                acc[c][mb] = __builtin_amdgcn_mfma_f32_16x16x32_f16(af, bfr[c], acc[c][mb], 0, 0, 0);
        }
    }
    // phase B: s = 2,3 from prefetched registers — no barrier needed
#pragma unroll
    for (int s2 = 0; s2 < 2; s2++) {
#pragma unroll
        for (int mb = 0; mb < 2; mb++) {
            f16x8 af = *(const f16x8*)(S + ((wr * 2 + mb) * 16 + m_) * 136 + (s2 + 2) * 32 + q_ * 8);
#pragma unroll
            for (int c = 0; c < 4; c++)
                acc[c][mb] = __builtin_amdgcn_mfma_f32_16x16x32_f16(af, bfB[s2][c], acc[c][mb], 0, 0, 0);
        }
    }
    // silu + sum over this wave's 32 rows (mb,r in-register, q_ via shfl)
    float scv4[4];
#pragma unroll
    for (int c = 0; c < 4; c++) {
        float scv = 0.0f;
#pragma unroll
        for (int mb = 0; mb < 2; mb++)
#pragma unroll
            for (int r = 0; r < 4; r++)
                scv += silu_f(acc[c][mb][r]);
        scv += __shfl_xor(scv, 16);
        scv += __shfl_xor(scv, 32);
        scv4[c] = scv;
    }
    __syncthreads();                   // all waves done reading S
    float* msum = (float*)S;           // overlay: 2 x 128 floats = 1 KB
    if (lane < 16) {
#pragma unroll
        for (int c = 0; c < 4; c++)
            msum[wr * 128 + (wc * 4 + c) * 16 + lane] = scv4[c];
    }
    __syncthreads();
    if (t < 128) {
        float mv = (msum[t] + msum[128 + t]) * (1.0f / 64.0f);
        m_out[ig * 128 + t] = (f16)mv;
    }
}

// Fused node update, 256 threads / 16 rows, column-split across 4 waves:
// u=silu([h|m]@nw1+nb1); x=h+u@nw2+nb2; h'=LN(x)*g+b; next a,b.
__global__ __launch_bounds__(256) void node_mid_kernel(
    const f16* h16, const f16* m16, const f16* nw1s, const f16* nw2s,
    const float* nb1C, const float* nb2C, const float* lngC, const float* lnbC,
    const f16* waN, const f16* wbN, const float* eb1N,
    f16* a16, f16* b16)
{
    __shared__ f16 relay[16 * 136];
    __shared__ float s1sh[4][16], s2sh[4][16];
    int t = threadIdx.x;
    int w = t >> 6, lane = t & 63;
    int row0 = blockIdx.x << 4;
    int m_ = lane & 15, q_ = lane >> 4;

    f16x8 af[8];
#pragma unroll
    for (int s = 0; s < 4; s++) {
        af[s]     = *(const f16x8*)(h16 + (row0 + m_) * 128 + s * 32 + q_ * 8);
        af[s + 4] = *(const f16x8*)(m16 + (row0 + m_) * 128 + s * 32 + q_ * 8);
    }
    // n1: wave w -> cols c = 2w, 2w+1
#pragma unroll
    for (int cc = 0; cc < 2; cc++) {
        int c = 2 * w + cc;
        float e = nb1C[c * 16 + m_];
        f32x4 acc = { e, e, e, e };
#pragma unroll
        for (int s = 0; s < 8; s++) {
            f16x8 bfr = *(const f16x8*)(nw1s + ((s * 8 + c) * 64 + lane) * 8);
            acc = __builtin_amdgcn_mfma_f32_16x16x32_f16(af[s], bfr, acc, 0, 0, 0);
        }
#pragma unroll
        for (int r = 0; r < 4; r++)
            relay[(q_ * 4 + r) * 136 + c * 16 + m_] = (f16)silu_f(acc[r]);
    }
    __syncthreads();
    f16x8 uf[4];
#pragma unroll
    for (int s = 0; s < 4; s++)
        uf[s] = *(const f16x8*)(relay + m_ * 136 + s * 32 + q_ * 8);
    // n2 + residual (this wave's 2 cols only)
    float x[2][4];
#pragma unroll
    for (int cc = 0; cc < 2; cc++) {
        int c = 2 * w + cc;
        float e = nb2C[c * 16 + m_];
        f32x4 acc = { e, e, e, e };
#pragma unroll
        for (int s = 0; s < 4; s++) {
            f16x8 bfr = *(const f16x8*)(nw2s + ((s * 8 + c) * 64 + lane) * 8);
            acc = __builtin_amdgcn_mfma_f32_16x16x32_f16(uf[s], bfr, acc, 0, 0, 0);
        }
#pragma unroll
        for (int r = 0; r < 4; r++)
            x[cc][r] = acc[r] + (float)h16[(row0 + q_ * 4 + r) * 128 + c * 16 + m_];
    }
    // LN: per-row partials over this wave's 2 cols, reduce over m_ then waves
    float s1p[4], s2p[4];
#pragma unroll
    for (int r = 0; r < 4; r++) {
        s1p[r] = x[0][r] + x[1][r];
        s2p[r] = x[0][r] * x[0][r] + x[1][r] * x[1][r];
    }
#pragma unroll
    for (int msk = 1; msk < 16; msk <<= 1)
#pragma unroll
        for (int r = 0; r < 4; r++) {
            s1p[r] += __shfl_xor(s1p[r], msk);
            s2p[r] += __shfl_xor(s2p[r], msk);
        }
    if (m_ == 0)
#pragma unroll
        for (int r = 0; r < 4; r++) {
            s1sh[w][q_ * 4 + r] = s1p[r];
            s2sh[w][q_ * 4 + r] = s2p[r];
        }
    __syncthreads();
    float mu[4], rs[4];
#pragma unroll
    for (int r = 0; r < 4; r++) {
        int row = q_ * 4 + r;
        float S1 = s1sh[0][row] + s1sh[1][row] + s1sh[2][row] + s1sh[3][row];
        float S2 = s2sh[0][row] + s2sh[1][row] + s2sh[2][row] + s2sh[3][row];
        mu[r] = S1 * (1.0f / 128.0f);
        float var = S2 * (1.0f / 128.0f) - mu[r] * mu[r];
        rs[r] = rsqrtf(var + 1e-5f);
    }
#pragma unroll
    for (int cc = 0; cc < 2; cc++) {
        int c = 2 * w + cc;
#pragma unroll
        for (int r = 0; r < 4; r++) {
            int col = c * 16 + m_;
            int row = row0 + q_ * 4 + r;
            float y = (x[cc][r] - mu[r]) * rs[r] * lngC[col] + lnbC[col];
            ((f16*)h16)[row * 128 + col] = (f16)y;
            relay[(q_ * 4 + r) * 136 + col] = (f16)y;
        }
    }
    __syncthreads();
    f16x8 hf[4];
#pragma unroll
    for (int s = 0; s < 4; s++)
        hf[s] = *(const f16x8*)(relay + m_ * 136 + s * 32 + q_ * 8);
    // next layer a,b (this wave's 2 cols)
#pragma unroll
    for (int mat = 0; mat < 2; mat++) {
        const f16* W = mat ? wbN : waN;
        f16* out     = mat ? b16 : a16;
#pragma unroll
        for (int cc = 0; cc < 2; cc++) {
            int c = 2 * w + cc;
            float init = mat ? 0.0f : eb1N[c * 16 + m_];
            f32x4 acc = { init, init, init, init };
#pragma unroll
            for (int s = 0; s < 4; s++) {
                f16x8 bfr = *(const f16x8*)(W + ((s * 8 + c) * 64 + lane) * 8);
                acc = __builtin_amdgcn_mfma_f32_16x16x32_f16(hf[s], bfr, acc, 0, 0, 0);
            }
#pragma unroll
            for (int r = 0; r < 4; r++)
                out[(row0 + q_ * 4 + r) * 128 + c * 16 + m_] = (f16)acc[r];
        }
    }
}

// Last layer: node update then out = h'@ow + ob. Same 256-thread split.
__global__ __launch_bounds__(256) void node_final_kernel(
    const void* pos_raw, const f16* h16, const f16* m16,
    const f16* nw1s, const f16* nw2s,
    const float* nb1C, const float* nb2C, const float* lngC, const float* lnbC,
    const float* owC, const float* obC, void* out)
{
    __shared__ f16 relay[16 * 136];
    __shared__ float s1sh[4][16], s2sh[4][16];
    __shared__ float psh[4][16][3];
    __shared__ int flgsh;
    int t = threadIdx.x;
    int w = t >> 6, lane = t & 63;
    int row0 = blockIdx.x << 4;
    int m_ = lane & 15, q_ = lane >> 4;

    if (t < 64) {
        int ex = (((const unsigned short*)pos_raw)[t * 2] >> 7) & 0xFF;
        unsigned long long mk = __ballot(ex >= 110 && ex <= 135);
        if (t == 0) flgsh = (__popcll(mk) >= 40) ? 1 : 0;
    }

    f16x8 af[8];
#pragma unroll
    for (int s = 0; s < 4; s++) {
        af[s]     = *(const f16x8*)(h16 + (row0 + m_) * 128 + s * 32 + q_ * 8);
        af[s + 4] = *(const f16x8*)(m16 + (row0 + m_) * 128 + s * 32 + q_ * 8);
    }
#pragma unroll
    for (int cc = 0; cc < 2; cc++) {
        int c = 2 * w + cc;
        float e = nb1C[c * 16 + m_];
        f32x4 acc = { e, e, e, e };
#pragma unroll
        for (int s = 0; s < 8; s++) {
            f16x8 bfr = *(const f16x8*)(nw1s + ((s * 8 + c) * 64 + lane) * 8);
            acc = __builtin_amdgcn_mfma_f32_16x16x32_f16(af[s], bfr, acc, 0, 0, 0);
        }
#pragma unroll
        for (int r = 0; r < 4; r++)
            relay[(q_ * 4 + r) * 136 + c * 16 + m_] = (f16)silu_f(acc[r]);
    }
    __syncthreads();
    f16x8 uf[4];
#pragma unroll
    for (int s = 0; s < 4; s++)
        uf[s] = *(const f16x8*)(relay + m_ * 136 + s * 32 + q_ * 8);
    float x[2][4];
#pragma unroll
    for (int cc = 0; cc < 2; cc++) {
        int c = 2 * w + cc;
        float e = nb2C[c * 16 + m_];
        f32x4 acc = { e, e, e, e };
#pragma unroll
        for (int s = 0; s < 4; s++) {
            f16x8 bfr = *(const f16x8*)(nw2s + ((s * 8 + c) * 64 + lane) * 8);
            acc = __builtin_amdgcn_mfma_f32_16x16x32_f16(uf[s], bfr, acc, 0, 0, 0);
        }
#pragma unroll
        for (int r = 0; r < 4; r++)
            x[cc][r] = acc[r] + (float)h16[(row0 + q_ * 4 + r) * 128 + c * 16 + m_];
    }
    float s1p[4], s2p[4];
#pragma unroll
    for (int r = 0; r < 4; r++) {
        s1p[r] = x[0][r] + x[1][r];
        s2p[r] = x[0][r] * x[0][r] + x[1][r] * x[1][r];
    }
#pragma unroll
    for (int msk = 1; msk < 16; msk <<= 1)
#pragma unroll
        for (int r = 0; r < 4; r++) {
            s1p[r] += __shfl_xor(s1p[r], msk);
            s2p[r] += __shfl_xor(s2p[r], msk);
        }
    if (m_ == 0)
#pragma unroll
        for (int r = 0; r < 4; r++) {
            s1sh[w][q_ * 4 + r] = s1p[r];
            s2sh[w][q_ * 4 + r] = s2p[r];
        }
    __syncthreads();
    // out projection: per-row partials over this wave's 2 cols
    float p[3][4];
#pragma unroll
    for (int r = 0; r < 4; r++) {
        int row = q_ * 4 + r;
        float S1 = s1sh[0][row] + s1sh[1][row] + s1sh[2][row] + s1sh[3][row];
        float S2 = s2sh[0][row] + s2sh[1][row] + s2sh[2][row] + s2sh[3][row];
        float mu = S1 * (1.0f / 128.0f);
        float var = S2 * (1.0f / 128.0f) - mu * mu;
        float rs = rsqrtf(var + 1e-5f);
        float p0 = 0.0f, p1 = 0.0f, p2 = 0.0f;
#pragma unroll
        for (int cc = 0; cc < 2; cc++) {
            int col = (2 * w + cc) * 16 + m_;
            float y = (x[cc][r] - mu) * rs * lngC[col] + lnbC[col];
            p0 += y * owC[col * 3 + 0];
            p1 += y * owC[col * 3 + 1];
            p2 += y * owC[col * 3 + 2];
        }
        p[0][r] = p0; p[1][r] = p1; p[2][r] = p2;
    }
#pragma unroll
    for (int msk = 1; msk < 16; msk <<= 1)
#pragma unroll
        for (int k = 0; k < 3; k++)
#pragma unroll
            for (int r = 0; r < 4; r++)
                p[k][r] += __shfl_xor(p[k][r], msk);
    if (m_ == 0)
#pragma unroll
        for (int r = 0; r < 4; r++)
#pragma unroll
            for (int k = 0; k < 3; k++)
                psh[w][q_ * 4 + r][k] = p[k][r];
    __syncthreads();
    if (t < 16) {
        int row = row0 + t;
        int bf = flgsh;
#pragma unroll
        for (int k = 0; k < 3; k++) {
            float v = psh[0][t][k] + psh[1][t][k] + psh[2][t][k] + psh[3][t][k]
                      + obC[k];
            if (bf) ((unsigned short*)out)[row * 3 + k] = f2bf(v);
            else    ((float*)out)[row * 3 + k] = v;
        }
    }
}

extern "C" void kernel_launch(void* const* d_in, const int* in_sizes, int n_in,
                              void* d_out, int out_size, void* d_ws, size_t ws_size,
                              hipStream_t stream)
{
    const int* an = (const int*)d_in[1];

    char* ws = (char*)d_ws;
    float* sc   = (float*)(ws + 1024);              // 70 KB
    f16*   Wswz = (f16*)(ws + (128u << 10));        // 768 KB
    f16*   h16  = (f16*)(ws + (1u << 20));          // 1 MB
    f16*   a16  = (f16*)(ws + (2u << 20));
    f16*   b16  = (f16*)(ws + (3u << 20));
    f16*   m16  = (f16*)(ws + (4u << 20));          // total 5 MB

    Ptrs ptrs;
    const int src_idx[14] = {0, 2, 3, 4, 5, 6, 7, 8, 9, 10, 11, 12, 13, 14};
    for (int k = 0; k < 14; k++) ptrs.p[k] = d_in[src_idx[k]];

    prep_kernel<<<261, 256, 0, stream>>>(ptrs, Wswz, sc);
    embed_ab_kernel<<<256, 256, 0, stream>>>(an, sc, Wswz, Wswz + 16384,
                                             sc + 14080, h16, a16, b16);
    for (int lay = 0; lay < 4; lay++) {
        const f16* wl = Wswz + lay * 98304;
        const float* wdC  = sc + 13568 + lay * 128;
        const float* eb2C = sc + 14592 + lay * 128;
        const float* nb1C = sc + 15104 + lay * 128;
        const float* nb2C = sc + 15616 + lay * 128;
        const float* lngC = sc + 16128 + lay * 128;
        const float* lnbC = sc + 16640 + lay * 128;

        edge_kernel<<<4096, 256, 0, stream>>>(sc, a16, b16, wl + 32768,
                                              eb2C, wdC, m16);
        if (lay < 3) {
            const f16* wlN = Wswz + (lay + 1) * 98304;
            node_mid_kernel<<<256, 256, 0, stream>>>(
                h16, m16, wl + 49152, wl + 81920, nb1C, nb2C, lngC, lnbC,
                wlN, wlN + 16384, sc + 14080 + (lay + 1) * 128, a16, b16);
        } else {
            node_final_kernel<<<256, 256, 0, stream>>>(
                d_in[0], h16, m16, wl + 49152, wl + 81920,
                nb1C, nb2C, lngC, lnbC,
                sc + 17152, sc + 17536, d_out);
        }
    }
}